// Round 8
// baseline (154.609 us; speedup 1.0000x reference)
//
#include <hip/hip_runtime.h>

#define T      1024
#define DFEAT  80
#define NF4    20          // DFEAT / 4
#define NF4P   22          // LDS row stride in float4: uniform 2-way banks (free)
#define W_CH   96          // h rows staged per LDS chunk
#define MARGIN 40.0f       // W^2 = d0^2 + MARGIN*sigma^2  -> tail cut at e^-20
#define SB     16          // s per block in align_kernel

// ---------------------------------------------------------------------------
// Prep: per batch, f64 cumsum -> centers; emit VALUE-SORTED centers + perm.
// b>=1: c[1..1023] ascending, c[0] is global max -> rotation [c1..c1023, c0].
// b==0: ref zeroes cs row -> c = d/2 in [0,0.5); 1024-bucket counting sort
// (bucket disorder <= 5e-4, absorbed by index slop in align_kernel).
// ---------------------------------------------------------------------------
__global__ __launch_bounds__(1024) void prep_kernel(
    const float* __restrict__ d, float* __restrict__ cls,
    unsigned short* __restrict__ perm)
{
    __shared__ double sd[T];
    __shared__ int    hist[T];
    __shared__ float  fmn[T];
    __shared__ float  fmx[T];

    const int b = blockIdx.x, t = threadIdx.x;
    const float dv = d[b * T + t];
    sd[t] = (double)dv;
    __syncthreads();
    for (int off = 1; off < T; off <<= 1) {          // Hillis-Steele f64 scan
        double add = (t >= off) ? sd[t - off] : 0.0;
        __syncthreads();
        sd[t] += add;
        __syncthreads();
    }
    double cs;
    if (b == 0)      cs = 0.0;               // ref quirk: whole batch-0 row
    else if (t == 0) cs = sd[T - 1];         // roll: row total wraps to t=0
    else             cs = sd[t - 1];
    const float val = (float)((double)dv * 0.5 + cs);

    if (b > 0) {
        const int j = (t == 0) ? (T - 1) : (t - 1);  // rotation = sorted order
        cls[b * T + j]  = val;
        perm[b * T + j] = (unsigned short)t;
    } else {
        fmn[t] = val; fmx[t] = val;
        __syncthreads();
        for (int off = T / 2; off > 0; off >>= 1) {
            if (t < off) {
                fmn[t] = fminf(fmn[t], fmn[t + off]);
                fmx[t] = fmaxf(fmx[t], fmx[t + off]);
            }
            __syncthreads();
        }
        const float cmin = fmn[0], cmax = fmx[0];
        const float scale = 1023.0f / fmaxf(cmax - cmin, 1e-20f);
        const int bkt = min(1023, max(0, (int)((val - cmin) * scale)));
        hist[t] = 0;
        __syncthreads();
        atomicAdd(&hist[bkt], 1);
        __syncthreads();
        const int cnt = hist[t];
        for (int off = 1; off < T; off <<= 1) {      // inclusive int scan
            int add = (t >= off) ? hist[t - off] : 0;
            __syncthreads();
            hist[t] += add;
            __syncthreads();
        }
        const int base = hist[t] - cnt;              // exclusive
        __syncthreads();
        hist[t] = base;
        __syncthreads();
        const int pos = atomicAdd(&hist[bkt], 1);
        cls[pos]  = val;
        perm[pos] = (unsigned short)t;
    }
}

// first index j in [0, T) with a[j] >= x ; returns T if none
__device__ __forceinline__ int lb(const float* a, float x) {
    int base = 0, len = T;
    while (len > 0) {
        int half = len >> 1;
        if (a[base + half] < x) { base += half + 1; len -= half + 1; }
        else len = half;
    }
    return base;
}

// ---------------------------------------------------------------------------
// align: one block = 16 s of one batch; each s owns a 16-lane group
// (q = feature quad 0..3, jp = 4-way j-parallel). Window over sorted centers;
// h rows gathered via perm into LDS (block window-union, chunked).
// Weights in REFERENCE f32 op order: v = -(dd*dd)/tss, w = exp(v - v0),
// v0 = -(d0*d0)/tss from the exact window min (round-4 lesson).
// ---------------------------------------------------------------------------
__global__ __launch_bounds__(256) void align_kernel(
    const float* __restrict__ h, const float* __restrict__ cls,
    const unsigned short* __restrict__ perm, const float* __restrict__ sigma,
    float* __restrict__ u, int size)
{
    __shared__ float  cl[T];
    __shared__ float4 hs[W_CH * NF4P];
    __shared__ int    jl_arr[SB], jh_arr[SB];

    const int b   = blockIdx.y;
    const int s0  = blockIdx.x * SB;
    const int tid = threadIdx.x;
    const int grp = tid >> 4;          // 0..15: which s
    const int q   = (tid >> 2) & 3;    // feature quad: k4 = q + 4*i5
    const int jp  = tid & 3;           // j-parallel lane
    const int s   = s0 + grp;

    const float* clsb = cls + (size_t)b * T;
    for (int i = tid; i < T; i += 256) cl[i] = clsb[i];
    __syncthreads();

    const float sg  = sigma[0];
    const float tss = 2.0f * sg * sg;
    const float ts  = (float)s + 1.5f;

    // approx nearest distance from insertion point +-16 (covers bucket slop)
    const int ins = lb(cl, ts);
    float d0a = 1e30f;
    {
        const int lo = max(0, ins - 16), hi = min(T, ins + 16);
        for (int j = lo + jp; j < hi; j += 4) d0a = fminf(d0a, fabsf(ts - cl[j]));
        d0a = fminf(d0a, __shfl_xor(d0a, 1));
        d0a = fminf(d0a, __shfl_xor(d0a, 2));
    }
    const float Ws  = sqrtf(fmaf(sg * sg, MARGIN, d0a * d0a));
    const int   jlo = max(0, lb(cl, ts - Ws) - 8);
    const int   jhi = min(T, lb(cl, ts + Ws) + 8);

    // pass 1: exact d0 over the window -> f32 max score (ref rounding)
    float d0 = 1e30f;
    for (int j = jlo + jp; j < jhi; j += 4) d0 = fminf(d0, fabsf(ts - cl[j]));
    d0 = fminf(d0, __shfl_xor(d0, 1));
    d0 = fminf(d0, __shfl_xor(d0, 2));
    const float v0 = -(d0 * d0) / tss;

    if ((tid & 15) == 0) { jl_arr[grp] = jlo; jh_arr[grp] = jhi; }
    __syncthreads();
    int rlo = jl_arr[0], rhi = jh_arr[0];
    #pragma unroll
    for (int g = 1; g < SB; ++g) {
        rlo = min(rlo, jl_arr[g]);
        rhi = max(rhi, jh_arr[g]);
    }

    float4 acc[5];
    #pragma unroll
    for (int i5 = 0; i5 < 5; ++i5) acc[i5] = make_float4(0.f, 0.f, 0.f, 0.f);
    float lsum = 0.f;

    const float4* hb4 = (const float4*)h + (size_t)b * T * NF4;
    const unsigned short* permb = perm + (size_t)b * T;

    for (int r0 = rlo; r0 < rhi; r0 += W_CH) {
        const int nr = min(W_CH, rhi - r0);
        __syncthreads();                       // previous chunk consumed
        for (int i = tid; i < nr * NF4; i += 256) {
            const int row = i / NF4, k = i - row * NF4;
            const int prow = permb[r0 + row];
            hs[row * NF4P + k] = hb4[(size_t)prow * NF4 + k];
        }
        __syncthreads();
        const int a = max(jlo, r0), e = min(jhi, r0 + nr);
        for (int j = a + jp; j < e; j += 4) {
            const float dd = ts - cl[j];
            const float v  = -(dd * dd) / tss;  // ref op order
            const float w  = __expf(v - v0);
            lsum += w;
            const float4* hr = &hs[(j - r0) * NF4P + q];
            #pragma unroll
            for (int i5 = 0; i5 < 5; ++i5) {
                const float4 hv = hr[4 * i5];
                acc[i5].x += w * hv.x; acc[i5].y += w * hv.y;
                acc[i5].z += w * hv.z; acc[i5].w += w * hv.w;
            }
        }
    }

    // reduce over the 4 jp lanes (xor butterfly, deterministic)
    lsum += __shfl_xor(lsum, 1);
    lsum += __shfl_xor(lsum, 2);
    #pragma unroll
    for (int i5 = 0; i5 < 5; ++i5) {
        acc[i5].x += __shfl_xor(acc[i5].x, 1); acc[i5].x += __shfl_xor(acc[i5].x, 2);
        acc[i5].y += __shfl_xor(acc[i5].y, 1); acc[i5].y += __shfl_xor(acc[i5].y, 2);
        acc[i5].z += __shfl_xor(acc[i5].z, 1); acc[i5].z += __shfl_xor(acc[i5].z, 2);
        acc[i5].w += __shfl_xor(acc[i5].w, 1); acc[i5].w += __shfl_xor(acc[i5].w, 2);
    }

    if (jp == 0) {
        const float inv = 1.0f / lsum;
        float4* ur = (float4*)(u + ((size_t)b * size + s) * DFEAT) + q;
        #pragma unroll
        for (int i5 = 0; i5 < 5; ++i5) {
            const float4 a4 = acc[i5];
            ur[4 * i5] = make_float4(a4.x * inv, a4.y * inv, a4.z * inv, a4.w * inv);
        }
    }
}

extern "C" void kernel_launch(void* const* d_in, const int* in_sizes, int n_in,
                              void* d_out, int out_size, void* d_ws, size_t ws_size,
                              hipStream_t stream) {
    const float* h     = (const float*)d_in[0];
    const float* d     = (const float*)d_in[1];
    const float* sigma = (const float*)d_in[2];
    float* u = (float*)d_out;

    const int bs   = in_sizes[1] / T;                 // 16
    const int size = out_size / (bs * DFEAT);         // 4096

    float*          cls  = (float*)d_ws;                       // bs*T f32
    unsigned short* perm = (unsigned short*)(cls + bs * T);    // bs*T u16

    hipLaunchKernelGGL(prep_kernel, dim3(bs), dim3(T), 0, stream, d, cls, perm);
    hipLaunchKernelGGL(align_kernel, dim3(size / SB, bs), dim3(256), 0, stream,
                       h, cls, perm, sigma, u, size);
}